// Round 10
// baseline (3543.289 us; speedup 1.0000x reference)
//
#include <hip/hip_runtime.h>

#define H 256
#define NLAYERS 6
typedef unsigned int uint32;
typedef unsigned short u16;

typedef __bf16 bf16;
typedef bf16 bf16x8 __attribute__((ext_vector_type(8)));
typedef float f32x4 __attribute__((ext_vector_type(4)));
typedef u16 u16x8 __attribute__((ext_vector_type(8)));

__device__ __forceinline__ float bf2f(u16 h) {
    return __uint_as_float(((uint32)h) << 16);
}
__device__ __forceinline__ u16 f2bf(float f) {
    uint32 u = __float_as_uint(f);
    u = u + 0x7FFFu + ((u >> 16) & 1u);   // round-nearest-even
    return (u16)(u >> 16);
}

__device__ __forceinline__ void glds16(const void* src, const char* ldsdst) {
    __builtin_amdgcn_global_load_lds(
        (const __attribute__((address_space(1))) void*)src,
        (__attribute__((address_space(3))) void*)ldsdst, 16, 0, 0);
}

// ---------------- sort pipeline ----------------

__global__ __launch_bounds__(256)
void count_kernel(const int* __restrict__ dst, int* __restrict__ deg, int E) {
    int e = blockIdx.x * 256 + threadIdx.x;
    if (e < E) atomicAdd(&deg[dst[e]], 1);
}

__global__ __launch_bounds__(256)
void invd_kernel(const int* __restrict__ deg, float* __restrict__ invd, int N) {
    int n = blockIdx.x * 256 + threadIdx.x;
    if (n < N) invd[n] = 1.f / fmaxf((float)deg[n], 1.f);
}

__global__ __launch_bounds__(256)
void scan1_kernel(const int* __restrict__ deg, int* __restrict__ bsum, int N) {
    __shared__ int s[256];
    int t = threadIdx.x;
    int i = blockIdx.x * 256 + t;
    s[t] = (i < N) ? deg[i] : 0;
    __syncthreads();
    for (int off = 128; off; off >>= 1) {
        if (t < off) s[t] += s[t + off];
        __syncthreads();
    }
    if (t == 0) bsum[blockIdx.x] = s[0];
}

__global__ __launch_bounds__(512)
void scan2_kernel(int* __restrict__ bsum, int nb) {
    __shared__ int s[512];
    int t = threadIdx.x;
    int v = (t < nb) ? bsum[t] : 0;
    s[t] = v;
    __syncthreads();
    for (int off = 1; off < 512; off <<= 1) {
        int x = (t >= off) ? s[t - off] : 0;
        __syncthreads();
        s[t] += x;
        __syncthreads();
    }
    if (t < nb) bsum[t] = s[t] - v;  // exclusive
}

__global__ __launch_bounds__(256)
void scan3_kernel(const int* __restrict__ deg, const int* __restrict__ bsum,
                  int* __restrict__ rowptr, int N, int E) {
    __shared__ int s[256];
    int t = threadIdx.x;
    int i = blockIdx.x * 256 + t;
    int v = (i < N) ? deg[i] : 0;
    s[t] = v;
    __syncthreads();
    for (int off = 1; off < 256; off <<= 1) {
        int x = (t >= off) ? s[t - off] : 0;
        __syncthreads();
        s[t] += x;
        __syncthreads();
    }
    if (i < N) rowptr[i] = s[t] - v + bsum[blockIdx.x];
    if (i == 0) rowptr[N] = E;
}

__global__ __launch_bounds__(256)
void scatter_kernel(const int* __restrict__ src, const int* __restrict__ dst,
                    const float* __restrict__ w, const int* __restrict__ rowptr,
                    int* __restrict__ cursor, int* __restrict__ srcS,
                    float* __restrict__ wS, int E) {
    int e = blockIdx.x * 256 + threadIdx.x;
    if (e >= E) return;
    int d = dst[e];
    int p = rowptr[d] + atomicAdd(&cursor[d], 1);
    srcS[p] = src[e];
    float4 wq;
    wq.x = w[(size_t)e * 3 + 0];
    wq.y = w[(size_t)e * 3 + 1];
    wq.z = w[(size_t)e * 3 + 2];
    wq.w = 0.f;
    *(float4*)&wS[(size_t)p * 4] = wq;
}

// ---------------- weight split (hi/lo bf16) ----------------

__global__ __launch_bounds__(256)
void wsplit_kernel(const float* __restrict__ W1, const float* __restrict__ W2,
                   const float* __restrict__ Wh1,
                   u16* __restrict__ W1hi, u16* __restrict__ W1lo,
                   u16* __restrict__ W2hi, u16* __restrict__ W2lo,
                   u16* __restrict__ Wh1hi, u16* __restrict__ Wh1lo)
{
    int i = blockIdx.x * 256 + threadIdx.x;
    float v; u16* ph; u16* pl; int o;
    if (i < 393216) {                 // 6*256*256
        int l = i >> 16, rem = i & 65535, r = rem >> 8, k = rem & 255;
        v = W1[(size_t)l * 66304 + (size_t)r * 259 + k];   // 256*259 = 66304
        ph = W1hi; pl = W1lo; o = i;
    } else if (i < 1179648) {         // + 6*256*512
        int j = i - 393216;
        v = W2[j];
        ph = W2hi; pl = W2lo; o = j;
    } else if (i < 1245184) {         // + 256*256
        int j = i - 1179648;
        v = Wh1[j];
        ph = Wh1hi; pl = Wh1lo; o = j;
    } else return;
    u16 hi = f2bf(v);
    ph[o] = hi;
    pl[o] = f2bf(v - bf2f(hi));
}

// extract edge-coefficient columns for ALL layers: cc[l][3][256]
__global__ void extract_kernel(const float* __restrict__ W1, float* __restrict__ ccAll)
{
    int l = blockIdx.x;
    int i = threadIdx.x;
    const float* W1l = W1 + (size_t)l * 66304;
    float* cc = ccAll + (size_t)l * 768;
    #pragma unroll
    for (int j = 0; j < 3; ++j)
        cc[j * 256 + i] = W1l[(size_t)i * 259 + 256 + j];
}

// ---------------- embedding gather + split ----------------

__global__ __launch_bounds__(256)
void emb_split_kernel(const int* __restrict__ gt, const float* __restrict__ emb,
                      u16* __restrict__ hHi, u16* __restrict__ hLo, int N) {
    size_t idx = (size_t)blockIdx.x * 256 + threadIdx.x;
    if (idx >= (size_t)N * 256) return;
    int n = (int)(idx >> 8), c = (int)(idx & 255);
    float v = emb[(size_t)gt[n] * 256 + c];
    u16 hi = f2bf(v);
    hHi[idx] = hi;
    hLo[idx] = f2bf(v - bf2f(hi));
}

// ---------------- split-bf16 MFMA GEMM ----------------
// C[M x 256] = act( Acat[M x KTOT] @ W^T + bias )
// BM=128, BN=256 (in-place safe), BK=32, 512 thr / 8 waves, grid-strided tiles.
// A-fragments: DIRECT global->VGPR (one dwordx4 per lane per frag) - no LDS.
// LDS: W only, double-buffered 2x32KB = 64KB -> 2 blocks/CU.
// W swizzle: slot = chunk ^ ((row>>1)&3)  -> 2-way LDS access (free).

#define WBUF 32768

template<bool MAIN>
__device__ __forceinline__ void do_compute(const char* B, const int* woff,
                                           const bf16x8* ah, const bf16x8* al,
                                           f32x4 (&acc)[4][4]) {
    #pragma unroll
    for (int nj = 0; nj < 4; ++nj) {
        bf16x8 wh = *(const bf16x8*)(B + woff[nj]);
        bf16x8 wl = *(const bf16x8*)(B + 16384 + woff[nj]);
        #pragma unroll
        for (int mi = 0; mi < 4; ++mi) {
            acc[mi][nj] = __builtin_amdgcn_mfma_f32_16x16x32_bf16(wh, ah[mi], acc[mi][nj], 0, 0, 0);
            acc[mi][nj] = __builtin_amdgcn_mfma_f32_16x16x32_bf16(wl, ah[mi], acc[mi][nj], 0, 0, 0);
            if (MAIN)
                acc[mi][nj] = __builtin_amdgcn_mfma_f32_16x16x32_bf16(wh, al[mi], acc[mi][nj], 0, 0, 0);
        }
    }
}

template<int KTOT, bool BIASRELU, bool WLO>
__global__ __launch_bounds__(512, 4)
void mfma_gemm_kernel(const u16* __restrict__ Ahi_, const u16* __restrict__ Alo_,
                      const u16* __restrict__ A2_,
                      const u16* __restrict__ Whi_, const u16* __restrict__ Wlo_,
                      const float* __restrict__ bias,
                      u16* __restrict__ Chi, u16* __restrict__ Clo,
                      int M, int ntiles)
{
    __shared__ __align__(128) char lds[2 * WBUF];
    const int tid = threadIdx.x;
    const int wv = tid >> 6;
    const int lane = tid & 63;
    const int lrow = lane & 15, koct = lane >> 4;
    const int rh = wv & 1, cg = wv >> 1;
    const int NT = KTOT / 32;

    // W fragment LDS byte offsets (static across tiles/steps)
    int woff[4];
    #pragma unroll
    for (int nj = 0; nj < 4; ++nj) {
        int r = cg * 64 + nj * 16 + lrow;
        woff[nj] = r * 64 + ((koct ^ ((r >> 1) & 3)) << 4);
    }

    // W staging source byte offsets (static): rows 0..127 and 128..255
    const int wrow0 = tid >> 2;
    const int wchk0 = (tid & 3) ^ ((wrow0 >> 1) & 3);
    const int wrow1 = 128 + (tid >> 2);
    const int wchk1 = (tid & 3) ^ ((wrow1 >> 1) & 3);
    const uint32 wsrc0 = (uint32)wrow0 * (KTOT * 2) + wchk0 * 16;
    const uint32 wsrc1 = (uint32)wrow1 * (KTOT * 2) + wchk1 * 16;
    const int ldst = wv * 1024;

    for (int tile = blockIdx.x; tile < ntiles; tile += gridDim.x) {
        const int m0 = tile * 128;

        // A fragment byte offsets (per mi), row-clamped; shared by hi/lo/A2
        uint32 aoffB[4];
        #pragma unroll
        for (int mi = 0; mi < 4; ++mi) {
            int row = m0 + rh * 64 + mi * 16 + lrow;
            if (row > M - 1) row = M - 1;
            aoffB[mi] = ((uint32)row * 256 + (uint32)koct * 8) * 2;
        }

        f32x4 acc[4][4] = {};

        // prologue: stage W tile 0 into buf0
        glds16((const char*)Whi_ + wsrc0, lds + ldst);
        glds16((const char*)Whi_ + wsrc1, lds + 8192 + ldst);
        glds16((const char*)Wlo_ + wsrc0, lds + 16384 + ldst);
        glds16((const char*)Wlo_ + wsrc1, lds + 24576 + ldst);
        asm volatile("s_waitcnt vmcnt(0)" ::: "memory");
        __builtin_amdgcn_s_barrier();
        __builtin_amdgcn_sched_barrier(0);

        #pragma unroll
        for (int t = 0; t < NT; ++t) {
            const char* bcur = lds + (t & 1) * WBUF;
            char* bnxt = lds + ((t + 1) & 1) * WBUF;
            if (t + 1 < NT) {
                glds16((const char*)Whi_ + wsrc0 + (t + 1) * 64, bnxt + ldst);
                glds16((const char*)Whi_ + wsrc1 + (t + 1) * 64, bnxt + 8192 + ldst);
                glds16((const char*)Wlo_ + wsrc0 + (t + 1) * 64, bnxt + 16384 + ldst);
                glds16((const char*)Wlo_ + wsrc1 + (t + 1) * 64, bnxt + 24576 + ldst);
            }
            bf16x8 ah[4], al[4];
            if (KTOT == 256 || t < 8) {
                #pragma unroll
                for (int mi = 0; mi < 4; ++mi) {
                    ah[mi] = *(const bf16x8*)((const char*)Ahi_ + aoffB[mi] + t * 64);
                    al[mi] = *(const bf16x8*)((const char*)Alo_ + aoffB[mi] + t * 64);
                }
                do_compute<true>(bcur, woff, ah, al, acc);
            } else {
                #pragma unroll
                for (int mi = 0; mi < 4; ++mi)
                    ah[mi] = *(const bf16x8*)((const char*)A2_ + aoffB[mi] + (t - 8) * 64);
                do_compute<false>(bcur, woff, ah, ah, acc);
            }
            asm volatile("s_waitcnt lgkmcnt(0) vmcnt(0)" ::: "memory");
            __builtin_amdgcn_s_barrier();
            __builtin_amdgcn_sched_barrier(0);
        }

        // epilogue: row = m0 + rh*64 + mi*16 + lrow, col = cg*64 + nj*16 + koct*4
        float4 bv[4];
        if (BIASRELU) {
            #pragma unroll
            for (int nj = 0; nj < 4; ++nj)
                bv[nj] = *(const float4*)&bias[cg * 64 + nj * 16 + koct * 4];
        }
        #pragma unroll
        for (int mi = 0; mi < 4; ++mi) {
            int row = m0 + rh * 64 + mi * 16 + lrow;
            if (row >= M) continue;
            #pragma unroll
            for (int nj = 0; nj < 4; ++nj) {
                f32x4 v = acc[mi][nj];
                if (BIASRELU) {
                    v[0] = fmaxf(v[0] + bv[nj].x, 0.f);
                    v[1] = fmaxf(v[1] + bv[nj].y, 0.f);
                    v[2] = fmaxf(v[2] + bv[nj].z, 0.f);
                    v[3] = fmaxf(v[3] + bv[nj].w, 0.f);
                }
                size_t o = (size_t)row * 256 + cg * 64 + nj * 16 + koct * 4;
                ushort4 ohi;
                ohi.x = f2bf(v[0]); ohi.y = f2bf(v[1]);
                ohi.z = f2bf(v[2]); ohi.w = f2bf(v[3]);
                *(ushort4*)&Chi[o] = ohi;
                if (WLO) {
                    ushort4 olo;
                    olo.x = f2bf(v[0] - bf2f(ohi.x));
                    olo.y = f2bf(v[1] - bf2f(ohi.y));
                    olo.z = f2bf(v[2] - bf2f(ohi.z));
                    olo.w = f2bf(v[3] - bf2f(ohi.w));
                    *(ushort4*)&Clo[o] = olo;
                }
            }
        }
    }
}

// ---------------- edge aggregation ----------------
// one wave per dst node; two 32-lane halves each cover all 256 cols (ushort8),
// process alternate edges, x4 unroll -> 8 independent gathers in flight/wave.

__global__ __launch_bounds__(256)
void edge_agg_kernel(const int* __restrict__ rowptr, const int* __restrict__ srcS,
                     const float* __restrict__ wS, const u16* __restrict__ T,
                     const float* __restrict__ cc, const float* __restrict__ invd,
                     u16* __restrict__ hN, int N) {
    int n = blockIdx.x * 4 + (threadIdx.x >> 6);
    int lane = threadIdx.x & 63;
    if (n >= N) return;
    const int half = lane >> 5;
    const int c32 = lane & 31;
    const int col0 = c32 * 8;

    float c0[8], c1[8], c2[8];
    #pragma unroll
    for (int j = 0; j < 3; ++j) {
        float4 lo4 = *(const float4*)&cc[j * 256 + col0];
        float4 hi4 = *(const float4*)&cc[j * 256 + col0 + 4];
        float* cj = (j == 0) ? c0 : (j == 1) ? c1 : c2;
        cj[0] = lo4.x; cj[1] = lo4.y; cj[2] = lo4.z; cj[3] = lo4.w;
        cj[4] = hi4.x; cj[5] = hi4.y; cj[6] = hi4.z; cj[7] = hi4.w;
    }

    float acc[8] = {};
    const int e0 = rowptr[n], e1 = rowptr[n + 1];
    int e = e0 + half;
    for (; e + 6 < e1; e += 8) {
        int s0 = srcS[e], s1 = srcS[e + 2], s2 = srcS[e + 4], s3 = srcS[e + 6];
        float4 wa = *(const float4*)&wS[(size_t)e * 4];
        float4 wb = *(const float4*)&wS[(size_t)(e + 2) * 4];
        float4 wc = *(const float4*)&wS[(size_t)(e + 4) * 4];
        float4 wd = *(const float4*)&wS[(size_t)(e + 6) * 4];
        u16x8 t0 = *(const u16x8*)&T[(size_t)s0 * 256 + col0];
        u16x8 t1 = *(const u16x8*)&T[(size_t)s1 * 256 + col0];
        u16x8 t2 = *(const u16x8*)&T[(size_t)s2 * 256 + col0];
        u16x8 t3 = *(const u16x8*)&T[(size_t)s3 * 256 + col0];
        #pragma unroll
        for (int q = 0; q < 8; ++q) {
            float x0 = fmaf(wa.x, c0[q], fmaf(wa.y, c1[q], fmaf(wa.z, c2[q], bf2f(t0[q]))));
            acc[q] += (x0 > 0.f) ? x0 : 0.01f * x0;
            float x1 = fmaf(wb.x, c0[q], fmaf(wb.y, c1[q], fmaf(wb.z, c2[q], bf2f(t1[q]))));
            acc[q] += (x1 > 0.f) ? x1 : 0.01f * x1;
            float x2 = fmaf(wc.x, c0[q], fmaf(wc.y, c1[q], fmaf(wc.z, c2[q], bf2f(t2[q]))));
            acc[q] += (x2 > 0.f) ? x2 : 0.01f * x2;
            float x3 = fmaf(wd.x, c0[q], fmaf(wd.y, c1[q], fmaf(wd.z, c2[q], bf2f(t3[q]))));
            acc[q] += (x3 > 0.f) ? x3 : 0.01f * x3;
        }
    }
    for (; e < e1; e += 2) {
        int s0 = srcS[e];
        float4 wa = *(const float4*)&wS[(size_t)e * 4];
        u16x8 t0 = *(const u16x8*)&T[(size_t)s0 * 256 + col0];
        #pragma unroll
        for (int q = 0; q < 8; ++q) {
            float x = fmaf(wa.x, c0[q], fmaf(wa.y, c1[q], fmaf(wa.z, c2[q], bf2f(t0[q]))));
            acc[q] += (x > 0.f) ? x : 0.01f * x;
        }
    }
    // combine the two halves (same cols)
    #pragma unroll
    for (int q = 0; q < 8; ++q) acc[q] += __shfl_xor(acc[q], 32);
    if (half == 0) {
        float sc = invd[n];
        u16x8 o;
        #pragma unroll
        for (int q = 0; q < 8; ++q) o[q] = f2bf(acc[q] * sc);
        *(u16x8*)&hN[(size_t)n * 256 + col0] = o;
    }
}

// ---------------- head: out = x @ Wh2^T + bh2 ----------------

__global__ __launch_bounds__(256)
void head_out_kernel(const u16* __restrict__ xhi, const u16* __restrict__ xlo,
                     const float* __restrict__ wh2,
                     const float* __restrict__ bh2, float* __restrict__ out, int N) {
    int n = blockIdx.x * 4 + (threadIdx.x >> 6);
    int lane = threadIdx.x & 63;
    if (n >= N) return;
    ushort4 hv = ((const ushort4*)(xhi + (size_t)n * H))[lane];
    ushort4 lv = ((const ushort4*)(xlo + (size_t)n * H))[lane];
    float4 wv = ((const float4*)wh2)[lane];
    float x0 = bf2f(hv.x) + bf2f(lv.x);
    float x1 = bf2f(hv.y) + bf2f(lv.y);
    float x2 = bf2f(hv.z) + bf2f(lv.z);
    float x3 = bf2f(hv.w) + bf2f(lv.w);
    float sum = x0 * wv.x + x1 * wv.y + x2 * wv.z + x3 * wv.w;
    #pragma unroll
    for (int off = 32; off; off >>= 1) sum += __shfl_xor(sum, off);
    if (lane == 0) out[n] = sum + bh2[0];
}

// ---------------- launch ----------------

extern "C" void kernel_launch(void* const* d_in, const int* in_sizes, int n_in,
                              void* d_out, int out_size, void* d_ws, size_t ws_size,
                              hipStream_t stream) {
    const int*   gate_type = (const int*)d_in[0];
    const int*   src  = (const int*)d_in[1];
    const int*   dst  = (const int*)d_in[2];
    const float* w    = (const float*)d_in[3];
    const float* emb  = (const float*)d_in[4];
    const float* W1   = (const float*)d_in[5];
    const float* W2   = (const float*)d_in[6];
    const float* b2   = (const float*)d_in[7];
    const float* Wh1  = (const float*)d_in[8];
    const float* bh1  = (const float*)d_in[9];
    const float* Wh2  = (const float*)d_in[10];
    const float* bh2  = (const float*)d_in[11];
    float* out = (float*)d_out;

    const int N = in_sizes[0];
    const int E = in_sizes[1];

    char* p = (char*)d_ws;
    auto alloc = [&](size_t bytes) -> char* {
        char* r = p;
        p += (bytes + 1023) & ~(size_t)1023;
        return r;
    };
    u16*   hHi   = (u16*)  alloc((size_t)N * H * 2);   // 51.2 MB
    u16*   hLo   = (u16*)  alloc((size_t)N * H * 2);   // 51.2 MB
    u16*   tBuf  = (u16*)  alloc((size_t)N * H * 2);   // 51.2 MB
    u16*   hNBuf = (u16*)  alloc((size_t)N * H * 2);   // 51.2 MB
    int*   srcS  = (int*)  alloc((size_t)E * 4);       //  3.2 MB
    float* wS    = (float*)alloc((size_t)E * 4 * 4);   // 12.8 MB
    int*   rowptr= (int*)  alloc((size_t)(N + 1) * 4);
    int*   cursor= (int*)  alloc((size_t)N * 4);
    int*   bsum  = (int*)  alloc(4096);
    float* invd  = (float*)alloc((size_t)N * 4);
    float* ccAll = (float*)alloc(6u * 768 * 4);
    u16*   W1hi  = (u16*)  alloc(6u * 256 * 256 * 2);
    u16*   W1lo  = (u16*)  alloc(6u * 256 * 256 * 2);
    u16*   W2hi  = (u16*)  alloc(6u * 256 * 512 * 2);
    u16*   W2lo  = (u16*)  alloc(6u * 256 * 512 * 2);
    u16*   Wh1hi = (u16*)  alloc(256u * 256 * 2);
    u16*   Wh1lo = (u16*)  alloc(256u * 256 * 2);

    const int nb1 = (N + 255) / 256;

    // counting sort of edges by dst + inv_deg
    hipMemsetAsync(cursor, 0, (size_t)N * 4, stream);
    count_kernel<<<(E + 255) / 256, 256, 0, stream>>>(dst, cursor, E);
    invd_kernel<<<nb1, 256, 0, stream>>>(cursor, invd, N);
    scan1_kernel<<<nb1, 256, 0, stream>>>(cursor, bsum, N);
    scan2_kernel<<<1, 512, 0, stream>>>(bsum, nb1);
    scan3_kernel<<<nb1, 256, 0, stream>>>(cursor, bsum, rowptr, N, E);
    hipMemsetAsync(cursor, 0, (size_t)N * 4, stream);
    scatter_kernel<<<(E + 255) / 256, 256, 0, stream>>>(src, dst, w, rowptr, cursor, srcS, wS, E);

    // weight split + coefficient extract + embedding
    wsplit_kernel<<<4864, 256, 0, stream>>>(W1, W2, Wh1, W1hi, W1lo, W2hi, W2lo, Wh1hi, Wh1lo);
    extract_kernel<<<6, 256, 0, stream>>>(W1, ccAll);
    emb_split_kernel<<<N, 256, 0, stream>>>(gate_type, emb, hHi, hLo, N);

    const int ntiles = (N + 127) / 128;
    const int ggrid = 512;
    for (int l = 0; l < NLAYERS; ++l) {
        // t = h @ W1a^T  (bf16x3, out single bf16)
        mfma_gemm_kernel<256, false, false><<<ggrid, 512, 0, stream>>>(
            hHi, hLo, nullptr, W1hi + (size_t)l * 65536, W1lo + (size_t)l * 65536,
            nullptr, tBuf, nullptr, N, ntiles);
        edge_agg_kernel<<<(N + 3) / 4, 256, 0, stream>>>(
            rowptr, srcS, wS, tBuf, ccAll + (size_t)l * 768, invd, hNBuf, N);
        // h = relu([h, hN] @ W2^T + b2)  (in-place: BN=256 full-width blocks)
        mfma_gemm_kernel<512, true, true><<<ggrid, 512, 0, stream>>>(
            hHi, hLo, hNBuf, W2hi + (size_t)l * 131072, W2lo + (size_t)l * 131072,
            b2 + (size_t)l * 256, hHi, hLo, N, ntiles);
    }
    // head
    mfma_gemm_kernel<256, true, true><<<ggrid, 512, 0, stream>>>(
        hHi, hLo, nullptr, Wh1hi, Wh1lo, bh1, hHi, hLo, N, ntiles);
    head_out_kernel<<<(N + 3) / 4, 256, 0, stream>>>(hHi, hLo, Wh2, bh2, out, N);
}

// Round 12
// 1849.888 us; speedup vs baseline: 1.9154x; 1.9154x over previous
//
#include <hip/hip_runtime.h>

#define H 256
#define NLAYERS 6
typedef unsigned int uint32;
typedef unsigned short u16;

typedef __bf16 bf16;
typedef bf16 bf16x8 __attribute__((ext_vector_type(8)));
typedef float f32x4 __attribute__((ext_vector_type(4)));
typedef u16 u16x8 __attribute__((ext_vector_type(8)));

__device__ __forceinline__ float bf2f(u16 h) {
    return __uint_as_float(((uint32)h) << 16);
}
__device__ __forceinline__ u16 f2bf(float f) {
    uint32 u = __float_as_uint(f);
    u = u + 0x7FFFu + ((u >> 16) & 1u);   // round-nearest-even
    return (u16)(u >> 16);
}

__device__ __forceinline__ void glds16(const void* src, const char* ldsdst) {
    __builtin_amdgcn_global_load_lds(
        (const __attribute__((address_space(1))) void*)src,
        (__attribute__((address_space(3))) void*)ldsdst, 16, 0, 0);
}

// ---------------- sort pipeline ----------------

__global__ __launch_bounds__(256)
void count_kernel(const int* __restrict__ dst, int* __restrict__ deg, int E) {
    int e = blockIdx.x * 256 + threadIdx.x;
    if (e < E) atomicAdd(&deg[dst[e]], 1);
}

__global__ __launch_bounds__(256)
void invd_kernel(const int* __restrict__ deg, float* __restrict__ invd, int N) {
    int n = blockIdx.x * 256 + threadIdx.x;
    if (n < N) invd[n] = 1.f / fmaxf((float)deg[n], 1.f);
}

__global__ __launch_bounds__(256)
void scan1_kernel(const int* __restrict__ deg, int* __restrict__ bsum, int N) {
    __shared__ int s[256];
    int t = threadIdx.x;
    int i = blockIdx.x * 256 + t;
    s[t] = (i < N) ? deg[i] : 0;
    __syncthreads();
    for (int off = 128; off; off >>= 1) {
        if (t < off) s[t] += s[t + off];
        __syncthreads();
    }
    if (t == 0) bsum[blockIdx.x] = s[0];
}

__global__ __launch_bounds__(512)
void scan2_kernel(int* __restrict__ bsum, int nb) {
    __shared__ int s[512];
    int t = threadIdx.x;
    int v = (t < nb) ? bsum[t] : 0;
    s[t] = v;
    __syncthreads();
    for (int off = 1; off < 512; off <<= 1) {
        int x = (t >= off) ? s[t - off] : 0;
        __syncthreads();
        s[t] += x;
        __syncthreads();
    }
    if (t < nb) bsum[t] = s[t] - v;  // exclusive
}

__global__ __launch_bounds__(256)
void scan3_kernel(const int* __restrict__ deg, const int* __restrict__ bsum,
                  int* __restrict__ rowptr, int N, int E) {
    __shared__ int s[256];
    int t = threadIdx.x;
    int i = blockIdx.x * 256 + t;
    int v = (i < N) ? deg[i] : 0;
    s[t] = v;
    __syncthreads();
    for (int off = 1; off < 256; off <<= 1) {
        int x = (t >= off) ? s[t - off] : 0;
        __syncthreads();
        s[t] += x;
        __syncthreads();
    }
    if (i < N) rowptr[i] = s[t] - v + bsum[blockIdx.x];
    if (i == 0) rowptr[N] = E;
}

__global__ __launch_bounds__(256)
void scatter_kernel(const int* __restrict__ src, const int* __restrict__ dst,
                    const float* __restrict__ w, const int* __restrict__ rowptr,
                    int* __restrict__ cursor, int* __restrict__ srcS,
                    float* __restrict__ wS, int E) {
    int e = blockIdx.x * 256 + threadIdx.x;
    if (e >= E) return;
    int d = dst[e];
    int p = rowptr[d] + atomicAdd(&cursor[d], 1);
    srcS[p] = src[e];
    float4 wq;
    wq.x = w[(size_t)e * 3 + 0];
    wq.y = w[(size_t)e * 3 + 1];
    wq.z = w[(size_t)e * 3 + 2];
    wq.w = 0.f;
    *(float4*)&wS[(size_t)p * 4] = wq;
}

// ---------------- weight split (hi/lo bf16) ----------------

__global__ __launch_bounds__(256)
void wsplit_kernel(const float* __restrict__ W1, const float* __restrict__ W2,
                   const float* __restrict__ Wh1,
                   u16* __restrict__ W1hi, u16* __restrict__ W1lo,
                   u16* __restrict__ W2hi, u16* __restrict__ W2lo,
                   u16* __restrict__ Wh1hi, u16* __restrict__ Wh1lo)
{
    int i = blockIdx.x * 256 + threadIdx.x;
    float v; u16* ph; u16* pl; int o;
    if (i < 393216) {                 // 6*256*256
        int l = i >> 16, rem = i & 65535, r = rem >> 8, k = rem & 255;
        v = W1[(size_t)l * 66304 + (size_t)r * 259 + k];   // 256*259 = 66304
        ph = W1hi; pl = W1lo; o = i;
    } else if (i < 1179648) {         // + 6*256*512
        int j = i - 393216;
        v = W2[j];
        ph = W2hi; pl = W2lo; o = j;
    } else if (i < 1245184) {         // + 256*256
        int j = i - 1179648;
        v = Wh1[j];
        ph = Wh1hi; pl = Wh1lo; o = j;
    } else return;
    u16 hi = f2bf(v);
    ph[o] = hi;
    pl[o] = f2bf(v - bf2f(hi));
}

// extract edge-coefficient columns for ALL layers: cc[l][3][256]
__global__ void extract_kernel(const float* __restrict__ W1, float* __restrict__ ccAll)
{
    int l = blockIdx.x;
    int i = threadIdx.x;
    const float* W1l = W1 + (size_t)l * 66304;
    float* cc = ccAll + (size_t)l * 768;
    #pragma unroll
    for (int j = 0; j < 3; ++j)
        cc[j * 256 + i] = W1l[(size_t)i * 259 + 256 + j];
}

// ---------------- embedding gather + split ----------------

__global__ __launch_bounds__(256)
void emb_split_kernel(const int* __restrict__ gt, const float* __restrict__ emb,
                      u16* __restrict__ hHi, u16* __restrict__ hLo, int N) {
    size_t idx = (size_t)blockIdx.x * 256 + threadIdx.x;
    if (idx >= (size_t)N * 256) return;
    int n = (int)(idx >> 8), c = (int)(idx & 255);
    float v = emb[(size_t)gt[n] * 256 + c];
    u16 hi = f2bf(v);
    hHi[idx] = hi;
    hLo[idx] = f2bf(v - bf2f(hi));
}

// ---------------- split-bf16 MFMA GEMM ----------------
// C[M x 256] = act( Acat[M x KTOT] @ W^T + bias )
// BM=128, BN=256 (full width -> in-place safe), BK=32, 512 thr / 8 waves.
// COUNTED-VMCNT double-buffered pipeline (T4): prologue stages tiles 0,1;
// per step: wait vmcnt(loads-of-next-stage) -> barrier -> compute(cur) ->
// barrier -> STAGE(cur, t+2). Loads stay in flight across barriers.
// Swizzle: slot = chunk ^ ((row>>1)&3)  -> exact 2-way LDS access (free).

#define LDS_AHI 0
#define LDS_ALO 8192
#define LDS_WHI 16384
#define LDS_WLO 32768
#define BUFSZ   49152

template<bool MAIN>
__device__ __forceinline__ void do_compute(const char* B, const int* aoff,
                                           const int* woff, f32x4 (&acc)[4][4]) {
    bf16x8 ah[4], al[4];
    #pragma unroll
    for (int mi = 0; mi < 4; ++mi) {
        ah[mi] = *(const bf16x8*)(B + LDS_AHI + aoff[mi]);
        if (MAIN) al[mi] = *(const bf16x8*)(B + LDS_ALO + aoff[mi]);
    }
    #pragma unroll
    for (int nj = 0; nj < 4; ++nj) {
        bf16x8 wh = *(const bf16x8*)(B + LDS_WHI + woff[nj]);
        bf16x8 wl = *(const bf16x8*)(B + LDS_WLO + woff[nj]);
        #pragma unroll
        for (int mi = 0; mi < 4; ++mi) {
            acc[mi][nj] = __builtin_amdgcn_mfma_f32_16x16x32_bf16(wh, ah[mi], acc[mi][nj], 0, 0, 0);
            acc[mi][nj] = __builtin_amdgcn_mfma_f32_16x16x32_bf16(wl, ah[mi], acc[mi][nj], 0, 0, 0);
            if (MAIN)
                acc[mi][nj] = __builtin_amdgcn_mfma_f32_16x16x32_bf16(wh, al[mi], acc[mi][nj], 0, 0, 0);
        }
    }
}

template<int KTOT, bool BIASRELU, bool WLO>
__global__ __launch_bounds__(512)
void mfma_gemm_kernel(const u16* __restrict__ Ahi_, const u16* __restrict__ Alo_,
                      const u16* __restrict__ A2_,
                      const u16* __restrict__ Whi_, const u16* __restrict__ Wlo_,
                      const float* __restrict__ bias,
                      u16* __restrict__ Chi, u16* __restrict__ Clo, int M)
{
    __shared__ __align__(128) char lds[2 * BUFSZ];
    const int tid = threadIdx.x;
    const int wv = tid >> 6;
    const int lane = tid & 63;
    const int m0 = blockIdx.x * 128;
    const int lrow = lane & 15, koct = lane >> 4;
    const int rh = wv & 1, cg = wv >> 1;

    // fragment LDS byte offsets (fixed across k-steps; swizzled by (row>>1)&3)
    int aoff[4], woff[4];
    #pragma unroll
    for (int mi = 0; mi < 4; ++mi) {
        int r = rh * 64 + mi * 16 + lrow;
        aoff[mi] = r * 64 + ((koct ^ ((r >> 1) & 3)) << 4);
    }
    #pragma unroll
    for (int nj = 0; nj < 4; ++nj) {
        int r = cg * 64 + nj * 16 + lrow;
        woff[nj] = r * 64 + ((koct ^ ((r >> 1) & 3)) << 4);
    }

    // A staging: 128 rows x 4 chunks = 512 -> 1 glds16/thread
    const int arow = tid >> 2;
    const int achk = (tid & 3) ^ ((arow >> 1) & 3);
    const long agrow = (long)((m0 + arow < M) ? (m0 + arow) : (M - 1));
    const char* Asrc_hi = (const char*)Ahi_ + agrow * 512 + achk * 16;
    const char* Asrc_lo = (const char*)Alo_ + agrow * 512 + achk * 16;
    const char* Asrc_2  = (const char*)A2_  + agrow * 512 + achk * 16;

    // W staging: 256 rows x 4 chunks = 1024 -> 2 glds16/thread
    int wrow0 = tid >> 2,          wchk0 = (tid & 3) ^ ((wrow0 >> 1) & 3);
    int wrow1 = (512 + tid) >> 2,  wchk1 = ((512 + tid) & 3) ^ ((wrow1 >> 1) & 3);
    const char* Wsrc_h0 = (const char*)Whi_ + (long)wrow0 * (KTOT * 2) + wchk0 * 16;
    const char* Wsrc_h1 = (const char*)Whi_ + (long)wrow1 * (KTOT * 2) + wchk1 * 16;
    const char* Wsrc_l0 = (const char*)Wlo_ + (long)wrow0 * (KTOT * 2) + wchk0 * 16;
    const char* Wsrc_l1 = (const char*)Wlo_ + (long)wrow1 * (KTOT * 2) + wchk1 * 16;

    // loads per stage: 6 (A hi+lo + 4 W) for k0<256, 5 (A2 + 4 W) for k0>=256
    auto STAGE = [&](char* B, int t) {
        const int k0 = t * 32;
        if (KTOT == 256 || k0 < 256) {
            glds16(Asrc_hi + k0 * 2, B + LDS_AHI + wv * 1024);
            glds16(Asrc_lo + k0 * 2, B + LDS_ALO + wv * 1024);
        } else {
            glds16(Asrc_2 + (k0 - 256) * 2, B + LDS_AHI + wv * 1024);
        }
        glds16(Wsrc_h0 + k0 * 2, B + LDS_WHI + wv * 1024);
        glds16(Wsrc_h1 + k0 * 2, B + LDS_WHI + 8192 + wv * 1024);
        glds16(Wsrc_l0 + k0 * 2, B + LDS_WLO + wv * 1024);
        glds16(Wsrc_l1 + k0 * 2, B + LDS_WLO + 8192 + wv * 1024);
    };

    f32x4 acc[4][4] = {};

    char* b0 = lds;
    char* b1 = lds + BUFSZ;

    // prologue: stage tiles 0 and 1 (12 loads in flight)
    STAGE(b0, 0);
    STAGE(b1, 1);

    const int NT = KTOT / 32;
    #pragma unroll
    for (int t = 0; t < NT; ++t) {
        char* bcur = (t & 1) ? b1 : b0;
        // wait until tile t's loads landed: outstanding-after = stage(t+1)'s count
        if (t + 1 < NT) {
            if (KTOT == 512 && t + 1 >= 8)
                asm volatile("s_waitcnt vmcnt(5)" ::: "memory");
            else
                asm volatile("s_waitcnt vmcnt(6)" ::: "memory");
        } else {
            asm volatile("s_waitcnt vmcnt(0)" ::: "memory");
        }
        __builtin_amdgcn_s_barrier();
        __builtin_amdgcn_sched_barrier(0);
        if (KTOT == 256 || t < 8) do_compute<true>(bcur, aoff, woff, acc);
        else                      do_compute<false>(bcur, aoff, woff, acc);
        __builtin_amdgcn_s_barrier();           // all waves done reading bcur
        __builtin_amdgcn_sched_barrier(0);
        if (t + 2 < NT) STAGE(bcur, t + 2);     // refill cur for tile t+2
    }

    // epilogue: row = m0 + rh*64 + mi*16 + lrow, col = cg*64 + nj*16 + koct*4
    float4 bv[4];
    if (BIASRELU) {
        #pragma unroll
        for (int nj = 0; nj < 4; ++nj)
            bv[nj] = *(const float4*)&bias[cg * 64 + nj * 16 + koct * 4];
    }
    #pragma unroll
    for (int mi = 0; mi < 4; ++mi) {
        int row = m0 + rh * 64 + mi * 16 + lrow;
        if (row >= M) continue;
        #pragma unroll
        for (int nj = 0; nj < 4; ++nj) {
            f32x4 v = acc[mi][nj];
            if (BIASRELU) {
                v[0] = fmaxf(v[0] + bv[nj].x, 0.f);
                v[1] = fmaxf(v[1] + bv[nj].y, 0.f);
                v[2] = fmaxf(v[2] + bv[nj].z, 0.f);
                v[3] = fmaxf(v[3] + bv[nj].w, 0.f);
            }
            size_t o = (size_t)row * 256 + cg * 64 + nj * 16 + koct * 4;
            ushort4 ohi;
            ohi.x = f2bf(v[0]); ohi.y = f2bf(v[1]);
            ohi.z = f2bf(v[2]); ohi.w = f2bf(v[3]);
            *(ushort4*)&Chi[o] = ohi;
            if (WLO) {
                ushort4 olo;
                olo.x = f2bf(v[0] - bf2f(ohi.x));
                olo.y = f2bf(v[1] - bf2f(ohi.y));
                olo.z = f2bf(v[2] - bf2f(ohi.z));
                olo.w = f2bf(v[3] - bf2f(ohi.w));
                *(ushort4*)&Clo[o] = olo;
            }
        }
    }
}

// ---------------- edge aggregation ----------------
// one wave per dst node; two 32-lane halves each cover all 256 cols (ushort8),
// process alternate edges, x4 unroll -> 8 independent gathers in flight/wave.

__global__ __launch_bounds__(256)
void edge_agg_kernel(const int* __restrict__ rowptr, const int* __restrict__ srcS,
                     const float* __restrict__ wS, const u16* __restrict__ T,
                     const float* __restrict__ cc, const float* __restrict__ invd,
                     u16* __restrict__ hN, int N) {
    int n = blockIdx.x * 4 + (threadIdx.x >> 6);
    int lane = threadIdx.x & 63;
    if (n >= N) return;
    const int half = lane >> 5;
    const int c32 = lane & 31;
    const int col0 = c32 * 8;

    float c0[8], c1[8], c2[8];
    #pragma unroll
    for (int j = 0; j < 3; ++j) {
        float4 lo4 = *(const float4*)&cc[j * 256 + col0];
        float4 hi4 = *(const float4*)&cc[j * 256 + col0 + 4];
        float* cj = (j == 0) ? c0 : (j == 1) ? c1 : c2;
        cj[0] = lo4.x; cj[1] = lo4.y; cj[2] = lo4.z; cj[3] = lo4.w;
        cj[4] = hi4.x; cj[5] = hi4.y; cj[6] = hi4.z; cj[7] = hi4.w;
    }

    float acc[8] = {};
    const int e0 = rowptr[n], e1 = rowptr[n + 1];
    int e = e0 + half;
    for (; e + 6 < e1; e += 8) {
        int s0 = srcS[e], s1 = srcS[e + 2], s2 = srcS[e + 4], s3 = srcS[e + 6];
        float4 wa = *(const float4*)&wS[(size_t)e * 4];
        float4 wb = *(const float4*)&wS[(size_t)(e + 2) * 4];
        float4 wc = *(const float4*)&wS[(size_t)(e + 4) * 4];
        float4 wd = *(const float4*)&wS[(size_t)(e + 6) * 4];
        u16x8 t0 = *(const u16x8*)&T[(size_t)s0 * 256 + col0];
        u16x8 t1 = *(const u16x8*)&T[(size_t)s1 * 256 + col0];
        u16x8 t2 = *(const u16x8*)&T[(size_t)s2 * 256 + col0];
        u16x8 t3 = *(const u16x8*)&T[(size_t)s3 * 256 + col0];
        #pragma unroll
        for (int q = 0; q < 8; ++q) {
            float x0 = fmaf(wa.x, c0[q], fmaf(wa.y, c1[q], fmaf(wa.z, c2[q], bf2f(t0[q]))));
            acc[q] += (x0 > 0.f) ? x0 : 0.01f * x0;
            float x1 = fmaf(wb.x, c0[q], fmaf(wb.y, c1[q], fmaf(wb.z, c2[q], bf2f(t1[q]))));
            acc[q] += (x1 > 0.f) ? x1 : 0.01f * x1;
            float x2 = fmaf(wc.x, c0[q], fmaf(wc.y, c1[q], fmaf(wc.z, c2[q], bf2f(t2[q]))));
            acc[q] += (x2 > 0.f) ? x2 : 0.01f * x2;
            float x3 = fmaf(wd.x, c0[q], fmaf(wd.y, c1[q], fmaf(wd.z, c2[q], bf2f(t3[q]))));
            acc[q] += (x3 > 0.f) ? x3 : 0.01f * x3;
        }
    }
    for (; e < e1; e += 2) {
        int s0 = srcS[e];
        float4 wa = *(const float4*)&wS[(size_t)e * 4];
        u16x8 t0 = *(const u16x8*)&T[(size_t)s0 * 256 + col0];
        #pragma unroll
        for (int q = 0; q < 8; ++q) {
            float x = fmaf(wa.x, c0[q], fmaf(wa.y, c1[q], fmaf(wa.z, c2[q], bf2f(t0[q]))));
            acc[q] += (x > 0.f) ? x : 0.01f * x;
        }
    }
    // combine the two halves (same cols)
    #pragma unroll
    for (int q = 0; q < 8; ++q) acc[q] += __shfl_xor(acc[q], 32);
    if (half == 0) {
        float sc = invd[n];
        u16x8 o;
        #pragma unroll
        for (int q = 0; q < 8; ++q) o[q] = f2bf(acc[q] * sc);
        *(u16x8*)&hN[(size_t)n * 256 + col0] = o;
    }
}

// ---------------- head: out = x @ Wh2^T + bh2 ----------------

__global__ __launch_bounds__(256)
void head_out_kernel(const u16* __restrict__ xhi, const u16* __restrict__ xlo,
                     const float* __restrict__ wh2,
                     const float* __restrict__ bh2, float* __restrict__ out, int N) {
    int n = blockIdx.x * 4 + (threadIdx.x >> 6);
    int lane = threadIdx.x & 63;
    if (n >= N) return;
    ushort4 hv = ((const ushort4*)(xhi + (size_t)n * H))[lane];
    ushort4 lv = ((const ushort4*)(xlo + (size_t)n * H))[lane];
    float4 wv = ((const float4*)wh2)[lane];
    float x0 = bf2f(hv.x) + bf2f(lv.x);
    float x1 = bf2f(hv.y) + bf2f(lv.y);
    float x2 = bf2f(hv.z) + bf2f(lv.z);
    float x3 = bf2f(hv.w) + bf2f(lv.w);
    float sum = x0 * wv.x + x1 * wv.y + x2 * wv.z + x3 * wv.w;
    #pragma unroll
    for (int off = 32; off; off >>= 1) sum += __shfl_xor(sum, off);
    if (lane == 0) out[n] = sum + bh2[0];
}

// ---------------- launch ----------------

extern "C" void kernel_launch(void* const* d_in, const int* in_sizes, int n_in,
                              void* d_out, int out_size, void* d_ws, size_t ws_size,
                              hipStream_t stream) {
    const int*   gate_type = (const int*)d_in[0];
    const int*   src  = (const int*)d_in[1];
    const int*   dst  = (const int*)d_in[2];
    const float* w    = (const float*)d_in[3];
    const float* emb  = (const float*)d_in[4];
    const float* W1   = (const float*)d_in[5];
    const float* W2   = (const float*)d_in[6];
    const float* b2   = (const float*)d_in[7];
    const float* Wh1  = (const float*)d_in[8];
    const float* bh1  = (const float*)d_in[9];
    const float* Wh2  = (const float*)d_in[10];
    const float* bh2  = (const float*)d_in[11];
    float* out = (float*)d_out;

    const int N = in_sizes[0];
    const int E = in_sizes[1];

    char* p = (char*)d_ws;
    auto alloc = [&](size_t bytes) -> char* {
        char* r = p;
        p += (bytes + 1023) & ~(size_t)1023;
        return r;
    };
    u16*   hHi   = (u16*)  alloc((size_t)N * H * 2);   // 51.2 MB
    u16*   hLo   = (u16*)  alloc((size_t)N * H * 2);   // 51.2 MB
    u16*   tBuf  = (u16*)  alloc((size_t)N * H * 2);   // 51.2 MB
    u16*   hNBuf = (u16*)  alloc((size_t)N * H * 2);   // 51.2 MB
    int*   srcS  = (int*)  alloc((size_t)E * 4);       //  3.2 MB
    float* wS    = (float*)alloc((size_t)E * 4 * 4);   // 12.8 MB
    int*   rowptr= (int*)  alloc((size_t)(N + 1) * 4);
    int*   cursor= (int*)  alloc((size_t)N * 4);
    int*   bsum  = (int*)  alloc(4096);
    float* invd  = (float*)alloc((size_t)N * 4);
    float* ccAll = (float*)alloc(6u * 768 * 4);
    u16*   W1hi  = (u16*)  alloc(6u * 256 * 256 * 2);
    u16*   W1lo  = (u16*)  alloc(6u * 256 * 256 * 2);
    u16*   W2hi  = (u16*)  alloc(6u * 256 * 512 * 2);
    u16*   W2lo  = (u16*)  alloc(6u * 256 * 512 * 2);
    u16*   Wh1hi = (u16*)  alloc(256u * 256 * 2);
    u16*   Wh1lo = (u16*)  alloc(256u * 256 * 2);

    const int nb1 = (N + 255) / 256;

    // counting sort of edges by dst + inv_deg
    hipMemsetAsync(cursor, 0, (size_t)N * 4, stream);
    count_kernel<<<(E + 255) / 256, 256, 0, stream>>>(dst, cursor, E);
    invd_kernel<<<nb1, 256, 0, stream>>>(cursor, invd, N);
    scan1_kernel<<<nb1, 256, 0, stream>>>(cursor, bsum, N);
    scan2_kernel<<<1, 512, 0, stream>>>(bsum, nb1);
    scan3_kernel<<<nb1, 256, 0, stream>>>(cursor, bsum, rowptr, N, E);
    hipMemsetAsync(cursor, 0, (size_t)N * 4, stream);
    scatter_kernel<<<(E + 255) / 256, 256, 0, stream>>>(src, dst, w, rowptr, cursor, srcS, wS, E);

    // weight split + coefficient extract + embedding
    wsplit_kernel<<<4864, 256, 0, stream>>>(W1, W2, Wh1, W1hi, W1lo, W2hi, W2lo, Wh1hi, Wh1lo);
    extract_kernel<<<6, 256, 0, stream>>>(W1, ccAll);
    emb_split_kernel<<<N, 256, 0, stream>>>(gate_type, emb, hHi, hLo, N);

    const int gm = (N + 127) / 128;
    for (int l = 0; l < NLAYERS; ++l) {
        // t = h @ W1a^T  (bf16x3, out single bf16)
        mfma_gemm_kernel<256, false, false><<<gm, 512, 0, stream>>>(
            hHi, hLo, nullptr, W1hi + (size_t)l * 65536, W1lo + (size_t)l * 65536,
            nullptr, tBuf, nullptr, N);
        edge_agg_kernel<<<(N + 3) / 4, 256, 0, stream>>>(
            rowptr, srcS, wS, tBuf, ccAll + (size_t)l * 768, invd, hNBuf, N);
        // h = relu([h, hN] @ W2^T + b2)  (in-place: BN=256 full-width blocks)
        mfma_gemm_kernel<512, true, true><<<gm, 512, 0, stream>>>(
            hHi, hLo, hNBuf, W2hi + (size_t)l * 131072, W2lo + (size_t)l * 131072,
            b2 + (size_t)l * 256, hHi, hLo, N);
    }
    // head
    mfma_gemm_kernel<256, true, true><<<gm, 512, 0, stream>>>(
        hHi, hLo, nullptr, Wh1hi, Wh1lo, bh1, hHi, hLo, N);
    head_out_kernel<<<(N + 3) / 4, 256, 0, stream>>>(hHi, hLo, Wh2, bh2, out, N);
}